// Round 5
// baseline (476.155 us; speedup 1.0000x reference)
//
#include <hip/hip_runtime.h>
#include <hip/hip_bf16.h>
#include <stdint.h>

#define EE 131072
#define DDEG 64

typedef __bf16 bf16_t;
typedef bf16_t bf16x8 __attribute__((ext_vector_type(8)));
typedef float floatx4 __attribute__((ext_vector_type(4)));

// ---------------- CN pair-count: one wave per edge, scalar b-row ----------------
__global__ __launch_bounds__(256)
void cn_kernel(const int* __restrict__ nbr, const int* __restrict__ tar,
               int* __restrict__ xcn, int* __restrict__ flags) {
    int wid  = (blockIdx.x * 256 + threadIdx.x) >> 6;
    int lane = threadIdx.x & 63;
    int s = __builtin_amdgcn_readfirstlane(tar[wid]);
    int d = __builtin_amdgcn_readfirstlane(tar[EE + wid]);
    int a = nbr[(size_t)s * DDEG + lane];                  // coalesced 256B row
    const int* __restrict__ brow = nbr + (size_t)d * DDEG; // uniform -> s_load
    int cnt = 0;
    #pragma unroll
    for (int k = 0; k < 64; ++k) {
        int bk = brow[k];
        cnt += __builtin_popcountll(__ballot(a == bk));
    }
    if (lane == 0) { xcn[wid] = cnt; flags[cnt] = 1; }   // benign race
}

// ---------------- CN-MLP table folded through lin_w1 (flags-gated, exact) ----
__global__ __launch_bounds__(256)
void table_kernel(const float* __restrict__ w1, const float* __restrict__ b1,
                  const float* __restrict__ w2, const float* __restrict__ b2,
                  const float* __restrict__ w3, const float* __restrict__ b3,
                  const float* __restrict__ beta, const float* __restrict__ lw1,
                  const int* __restrict__ flags, float* __restrict__ T2) {
    int v = blockIdx.x;
    if (flags[v] == 0) return;    // uniform, before any barrier
    int h = threadIdx.x;
    __shared__ float t1[256];
    __shared__ float t2[256];
    __shared__ float t3[256];
    float fv = (float)v;
    t1[h] = fmaxf(fv * w1[h] + b1[h], 0.f);
    __syncthreads();
    float s = b2[h];
    for (int k = 0; k < 256; ++k) s += t1[k] * w2[k * 256 + h];
    t2[h] = fmaxf(s, 0.f);
    __syncthreads();
    s = b3[h];
    for (int k = 0; k < 256; ++k) s += t2[k] * w3[k * 256 + h];
    t3[h] = s * beta[0];
    __syncthreads();
    s = 0.f;
    for (int k = 0; k < 256; ++k) s += t3[k] * lw1[k * 256 + h];
    T2[(size_t)v * 256 + h] = s;
}

// ---------------- prep: Wt1 transpose | Mt=ij_w2@lin_w1 (bf16 [n][k]) |
//                  cvec=ij_b2@lin_w1+lin_b1 ----------------------------------
__global__ __launch_bounds__(256)
void prep_kernel(const float* __restrict__ ij_w1, bf16_t* __restrict__ Wt1,
                 const float* __restrict__ w2, const float* __restrict__ lw1,
                 bf16_t* __restrict__ Mt,
                 const float* __restrict__ b2, const float* __restrict__ lb1,
                 float* __restrict__ cvec) {
    __shared__ float tile[32][33];
    __shared__ float S[256][33];
    __shared__ float red[256];
    int bid = blockIdx.x;
    int t = threadIdx.x;
    if (bid < 64) {
        // transpose ij_w1 fp32[k][n] -> bf16 Wt1[n][k]
        int bx = bid & 7, by = bid >> 3;
        int tx = t & 31, ty = t >> 5;
        #pragma unroll
        for (int r = 0; r < 32; r += 8)
            tile[ty + r][tx] = ij_w1[(by * 32 + ty + r) * 256 + bx * 32 + tx];
        __syncthreads();
        #pragma unroll
        for (int r = 0; r < 32; r += 8)
            Wt1[(bx * 32 + ty + r) * 256 + by * 32 + tx] = (bf16_t)tile[tx][ty + r];
    } else if (bid < 320) {
        int b = bid - 64;
        int cc = t & 31, abase = t >> 5;
        float acc = 0.f;
        for (int c0 = 0; c0 < 256; c0 += 32) {
            __syncthreads();
            #pragma unroll
            for (int r = 0; r < 32; ++r) {
                int a = r * 8 + abase;
                S[a][cc] = w2[a * 256 + c0 + cc];
            }
            __syncthreads();
            #pragma unroll 8
            for (int c2 = 0; c2 < 32; ++c2) {
                float wv = lw1[(c0 + c2) * 256 + b];   // uniform -> scalar
                acc += S[t][c2] * wv;
            }
        }
        Mt[(size_t)b * 256 + t] = (bf16_t)acc;
    } else {
        int b = bid - 320;
        red[t] = b2[t] * lw1[t * 256 + b];
        __syncthreads();
        for (int s = 128; s > 0; s >>= 1) {
            if (t < s) red[t] += red[t + s];
            __syncthreads();
        }
        if (t == 0) cvec[b] = red[0] + lb1[b];
    }
}

// ---------------- fused, barrier-free GEMMs with direct fragment loads --------
// g = relu((xi*xj)@W1 + b1)  [A,B direct from global, no LDS, no barriers]
// z = relu(g@M + cvec + T2[xcn]); out = z@lin_w2 + lin_b2
// g round-trips through LDS (gt) with ONE barrier.
__global__ __launch_bounds__(256, 3)
void fused_kernel(const float* __restrict__ x, const int* __restrict__ tar,
                  const bf16_t* __restrict__ Wt1, const float* __restrict__ b1,
                  const bf16_t* __restrict__ Mt, const float* __restrict__ cvec,
                  const float* __restrict__ T2, const int* __restrict__ xcn,
                  const float* __restrict__ w2, const float* __restrict__ b2s,
                  float* __restrict__ out) {
    __shared__ __align__(16) bf16_t gt[64 * 264];   // 33792 B
    __shared__ float rowacc[64];

    const int tid  = threadIdx.x;
    const int lane = tid & 63;
    const int wc   = tid >> 6;          // wave = col quarter 0..3
    const int quad = lane >> 4;
    const int l16  = lane & 15;
    const int e0   = blockIdx.x * 64;

    // A-row base pointers: rows l16 + 16*i
    const float* xip[4];
    const float* xjp[4];
    #pragma unroll
    for (int i = 0; i < 4; ++i) {
        int e = e0 + i * 16 + l16;
        xip[i] = x + (size_t)tar[e] * 256;
        xjp[i] = x + (size_t)tar[EE + e] * 256;
    }

    floatx4 acc[4][4];
    #pragma unroll
    for (int i = 0; i < 4; ++i)
        #pragma unroll
        for (int j = 0; j < 4; ++j)
            acc[i][j] = (floatx4){0.f, 0.f, 0.f, 0.f};

    // ---- GEMM1: (xi*xj) @ W1, fragments straight from global ----
    #pragma unroll 2
    for (int kc = 0; kc < 8; ++kc) {
        const int k0 = kc * 32 + quad * 8;
        bf16x8 bfr[4];
        #pragma unroll
        for (int j = 0; j < 4; ++j)
            bfr[j] = *(const bf16x8*)(Wt1 + (size_t)(wc * 64 + j * 16 + l16) * 256 + k0);
        bf16x8 af[4];
        #pragma unroll
        for (int i = 0; i < 4; ++i) {
            float4 u0 = *(const float4*)(xip[i] + k0);
            float4 u1 = *(const float4*)(xip[i] + k0 + 4);
            float4 v0 = *(const float4*)(xjp[i] + k0);
            float4 v1 = *(const float4*)(xjp[i] + k0 + 4);
            bf16x8 t;
            t[0] = (bf16_t)(u0.x * v0.x); t[1] = (bf16_t)(u0.y * v0.y);
            t[2] = (bf16_t)(u0.z * v0.z); t[3] = (bf16_t)(u0.w * v0.w);
            t[4] = (bf16_t)(u1.x * v1.x); t[5] = (bf16_t)(u1.y * v1.y);
            t[6] = (bf16_t)(u1.z * v1.z); t[7] = (bf16_t)(u1.w * v1.w);
            af[i] = t;
        }
        #pragma unroll
        for (int i = 0; i < 4; ++i)
            #pragma unroll
            for (int j = 0; j < 4; ++j)
                acc[i][j] = __builtin_amdgcn_mfma_f32_16x16x32_bf16(
                                af[i], bfr[j], acc[i][j], 0, 0, 0);
    }

    // ---- epilogue 1: g tile -> LDS (bf16) ----
    #pragma unroll
    for (int j = 0; j < 4; ++j) {
        int col  = wc * 64 + j * 16 + l16;
        float bv = b1[col];
        #pragma unroll
        for (int i = 0; i < 4; ++i)
            #pragma unroll
            for (int r = 0; r < 4; ++r) {
                int row = i * 16 + quad * 4 + r;
                gt[row * 264 + col] = (bf16_t)fmaxf(acc[i][j][r] + bv, 0.f);
            }
    }
    #pragma unroll
    for (int i = 0; i < 4; ++i)
        #pragma unroll
        for (int j = 0; j < 4; ++j)
            acc[i][j] = (floatx4){0.f, 0.f, 0.f, 0.f};
    __syncthreads();                       // the ONLY staging barrier
    if (tid < 64) rowacc[tid] = 0.f;

    // ---- GEMM2: g @ M; A from LDS, B straight from global (L2-hot) ----
    #pragma unroll 2
    for (int kc = 0; kc < 8; ++kc) {
        const int k0 = kc * 32 + quad * 8;
        bf16x8 af[4], bfr[4];
        #pragma unroll
        for (int j = 0; j < 4; ++j)
            bfr[j] = *(const bf16x8*)(Mt + (size_t)(wc * 64 + j * 16 + l16) * 256 + k0);
        #pragma unroll
        for (int i = 0; i < 4; ++i)
            af[i] = *(const bf16x8*)(&gt[(i * 16 + l16) * 264 + k0]);
        #pragma unroll
        for (int i = 0; i < 4; ++i)
            #pragma unroll
            for (int j = 0; j < 4; ++j)
                acc[i][j] = __builtin_amdgcn_mfma_f32_16x16x32_bf16(
                                af[i], bfr[j], acc[i][j], 0, 0, 0);
    }

    // ---- final epilogue: +cvec +T2[xcn], relu, dot lin_w2, row-reduce ----
    int xv[16];
    #pragma unroll
    for (int i = 0; i < 4; ++i)
        #pragma unroll
        for (int r = 0; r < 4; ++r)
            xv[i * 4 + r] = xcn[e0 + i * 16 + quad * 4 + r];

    float pr[16];
    #pragma unroll
    for (int t = 0; t < 16; ++t) pr[t] = 0.f;
    #pragma unroll
    for (int j = 0; j < 4; ++j) {
        int col  = wc * 64 + j * 16 + l16;
        float cv = cvec[col];
        float wv = w2[col];
        #pragma unroll
        for (int i = 0; i < 4; ++i)
            #pragma unroll
            for (int r = 0; r < 4; ++r) {
                float t2v = T2[(size_t)xv[i * 4 + r] * 256 + col];
                float v = fmaxf(acc[i][j][r] + cv + t2v, 0.f);
                pr[i * 4 + r] += v * wv;
            }
    }
    #pragma unroll
    for (int off = 1; off < 16; off <<= 1)
        #pragma unroll
        for (int t = 0; t < 16; ++t)
            pr[t] += __shfl_xor(pr[t], off, 64);
    __syncthreads();   // rowacc init visible before atomics
    if (l16 == 0) {
        #pragma unroll
        for (int i = 0; i < 4; ++i)
            #pragma unroll
            for (int r = 0; r < 4; ++r)
                atomicAdd(&rowacc[i * 16 + quad * 4 + r], pr[i * 4 + r]);
    }
    __syncthreads();
    if (tid < 64) out[e0 + tid] = rowacc[tid] + b2s[0];
}

extern "C" void kernel_launch(void* const* d_in, const int* in_sizes, int n_in,
                              void* d_out, int out_size, void* d_ws, size_t ws_size,
                              hipStream_t stream) {
    const float* x      = (const float*)d_in[0];
    const int*   nbr    = (const int*)  d_in[1];
    const int*   tar    = (const int*)  d_in[2];
    const float* beta   = (const float*)d_in[3];
    const float* cn_w1  = (const float*)d_in[4];
    const float* cn_b1  = (const float*)d_in[5];
    const float* cn_w2  = (const float*)d_in[6];
    const float* cn_b2  = (const float*)d_in[7];
    const float* cn_w3  = (const float*)d_in[8];
    const float* cn_b3  = (const float*)d_in[9];
    const float* ij_w1  = (const float*)d_in[10];
    const float* ij_b1  = (const float*)d_in[11];
    const float* ij_w2  = (const float*)d_in[12];
    const float* ij_b2  = (const float*)d_in[13];
    const float* lin_w1 = (const float*)d_in[14];
    const float* lin_b1 = (const float*)d_in[15];
    const float* lin_w2 = (const float*)d_in[16];
    const float* lin_b2 = (const float*)d_in[17];

    char* ws = (char*)d_ws;
    float*  T2    = (float*) (ws + 0);         // 4097*256*4 = 4,195,328
    int*    flags = (int*)   (ws + 4195328);   // 4097*4 (padded)
    int*    xcn   = (int*)   (ws + 4212224);   // E*4 = 524288
    bf16_t* Wt1   = (bf16_t*)(ws + 4736512);   // 256*256*2
    bf16_t* Mt    = (bf16_t*)(ws + 4867584);   // 256*256*2
    float*  cvec  = (float*) (ws + 4998656);   // 256*4

    hipMemsetAsync(flags, 0, 4097 * sizeof(int), stream);
    cn_kernel<<<EE / 4, 256, 0, stream>>>(nbr, tar, xcn, flags);
    prep_kernel<<<576, 256, 0, stream>>>(ij_w1, Wt1, ij_w2, lin_w1, Mt,
                                         ij_b2, lin_b1, cvec);
    table_kernel<<<4097, 256, 0, stream>>>(cn_w1, cn_b1, cn_w2, cn_b2,
                                           cn_w3, cn_b3, beta, lin_w1, flags, T2);
    fused_kernel<<<EE / 64, 256, 0, stream>>>(x, tar, Wt1, ij_b1, Mt, cvec,
                                              T2, xcn, lin_w2, lin_b2,
                                              (float*)d_out);
}

// Round 6
// 390.865 us; speedup vs baseline: 1.2182x; 1.2182x over previous
//
#include <hip/hip_runtime.h>
#include <hip/hip_bf16.h>
#include <stdint.h>

#define EE 131072
#define DDEG 64

typedef __bf16 bf16_t;
typedef bf16_t bf16x8 __attribute__((ext_vector_type(8)));
typedef float floatx4 __attribute__((ext_vector_type(4)));

// ---------------- pre: cn | Wt1 transpose | Mt | cvec | T2 table --------------
// grid: [0,64) transpose, [64,320) Mt, [320,576) cvec, [576,1088) T2 v=0..511,
//        [1088, 1088+32768) cn (one wave per edge).
__global__ __launch_bounds__(256)
void pre_kernel(const int* __restrict__ nbr, const int* __restrict__ tar,
                int* __restrict__ xcn,
                const float* __restrict__ ij_w1, bf16_t* __restrict__ Wt1,
                const float* __restrict__ w2, const float* __restrict__ lw1,
                bf16_t* __restrict__ Mt,
                const float* __restrict__ b2, const float* __restrict__ lb1,
                float* __restrict__ cvec,
                const float* __restrict__ cw1, const float* __restrict__ cb1,
                const float* __restrict__ cw2, const float* __restrict__ cb2,
                const float* __restrict__ cw3, const float* __restrict__ cb3,
                const float* __restrict__ beta, float* __restrict__ T2) {
    __shared__ __align__(16) char arena[33792];
    const int bid = blockIdx.x;
    const int t = threadIdx.x;

    if (bid >= 1088) {
        // ---- cn: one wave per edge; b-row via wave-uniform scalar loads ----
        int wid  = (bid - 1088) * 4 + (t >> 6);
        int lane = t & 63;
        int s = __builtin_amdgcn_readfirstlane(tar[wid]);
        int d = __builtin_amdgcn_readfirstlane(tar[EE + wid]);
        int a = nbr[(size_t)s * DDEG + lane];
        const int* __restrict__ brow = nbr + (size_t)d * DDEG;
        int cnt = 0;
        #pragma unroll
        for (int k = 0; k < 64; ++k)
            cnt += __builtin_popcountll(__ballot(a == brow[k]));
        if (lane == 0) xcn[wid] = cnt;
        return;
    }

    if (bid < 64) {
        // ---- transpose ij_w1 fp32[k][n] -> bf16 Wt1[n][k] ----
        float (*tile)[33] = (float (*)[33])arena;
        int bx = bid & 7, by = bid >> 3;
        int tx = t & 31, ty = t >> 5;
        #pragma unroll
        for (int r = 0; r < 32; r += 8)
            tile[ty + r][tx] = ij_w1[(by * 32 + ty + r) * 256 + bx * 32 + tx];
        __syncthreads();
        #pragma unroll
        for (int r = 0; r < 32; r += 8)
            Wt1[(bx * 32 + ty + r) * 256 + by * 32 + tx] = (bf16_t)tile[tx][ty + r];
    } else if (bid < 320) {
        // ---- Mt[b][a] = sum_c ij_w2[a][c] * lin_w1[c][b] (bf16 [n][k]) ----
        float (*S)[33] = (float (*)[33])arena;
        int b = bid - 64;
        int cc = t & 31, abase = t >> 5;
        float acc = 0.f;
        for (int c0 = 0; c0 < 256; c0 += 32) {
            __syncthreads();
            #pragma unroll
            for (int r = 0; r < 32; ++r) {
                int a = r * 8 + abase;
                S[a][cc] = w2[a * 256 + c0 + cc];
            }
            __syncthreads();
            #pragma unroll 8
            for (int c2 = 0; c2 < 32; ++c2) {
                float wv = lw1[(c0 + c2) * 256 + b];   // uniform -> scalar
                acc += S[t][c2] * wv;
            }
        }
        Mt[(size_t)b * 256 + t] = (bf16_t)acc;
    } else if (bid < 576) {
        // ---- cvec[b] = ij_b2 @ lin_w1 + lin_b1 ----
        float* red = (float*)arena;
        int b = bid - 320;
        red[t] = b2[t] * lw1[t * 256 + b];
        __syncthreads();
        for (int s = 128; s > 0; s >>= 1) {
            if (t < s) red[t] += red[t + s];
            __syncthreads();
        }
        if (t == 0) cvec[b] = red[0] + lb1[b];
    } else {
        // ---- T2[v] = (cn_mlp(v) * beta) @ lin_w1, v = 0..511 unconditional ----
        float* t1 = (float*)arena;
        float* t2 = (float*)(arena + 1024);
        float* t3 = (float*)(arena + 2048);
        int v = bid - 576;
        float fv = (float)v;
        t1[t] = fmaxf(fv * cw1[t] + cb1[t], 0.f);
        __syncthreads();
        float s = cb2[t];
        for (int k = 0; k < 256; ++k) s += t1[k] * cw2[k * 256 + t];
        t2[t] = fmaxf(s, 0.f);
        __syncthreads();
        s = cb3[t];
        for (int k = 0; k < 256; ++k) s += t2[k] * cw3[k * 256 + t];
        t3[t] = s * beta[0];
        __syncthreads();
        s = 0.f;
        for (int k = 0; k < 256; ++k) s += t3[k] * lw1[k * 256 + t];
        T2[(size_t)v * 256 + t] = s;
    }
}

// ---------------- fused: A staged ONCE to LDS (full K), 3 barriers total ------
// g = relu((xi*xj)@W1 + b1); z = relu(g@M + cvec + T2[xcn]); out = z@w2 + b2s
__global__ __launch_bounds__(256, 4)
void fused_kernel(const float* __restrict__ x, const int* __restrict__ tar,
                  const bf16_t* __restrict__ Wt1, const float* __restrict__ b1,
                  const bf16_t* __restrict__ Mt, const float* __restrict__ cvec,
                  const float* __restrict__ T2, const int* __restrict__ xcn,
                  const float* __restrict__ w2, const float* __restrict__ b2s,
                  float* __restrict__ out) {
    __shared__ __align__(16) bf16_t X[64 * 264];   // A tile, then g tile
    __shared__ float rowacc[64];

    const int tid  = threadIdx.x;
    const int lane = tid & 63;
    const int wc   = tid >> 6;          // wave = col quarter 0..3
    const int quad = lane >> 4;
    const int l16  = lane & 15;
    const int e0   = blockIdx.x * 64;

    // ---- stage A = bf16(xi * xj), full K=256, coalesced, once ----
    {
        const int srow   = tid >> 2;       // 4 threads per row
        const int skbase = (tid & 3) * 8;
        int e = e0 + srow;
        const float* xi = x + (size_t)tar[e] * 256;
        const float* xj = x + (size_t)tar[EE + e] * 256;
        #pragma unroll 2
        for (int kc = 0; kc < 8; ++kc) {
            int k0 = kc * 32 + skbase;
            float4 u0 = *(const float4*)(xi + k0);
            float4 u1 = *(const float4*)(xi + k0 + 4);
            float4 v0 = *(const float4*)(xj + k0);
            float4 v1 = *(const float4*)(xj + k0 + 4);
            bf16x8 p;
            p[0] = (bf16_t)(u0.x * v0.x); p[1] = (bf16_t)(u0.y * v0.y);
            p[2] = (bf16_t)(u0.z * v0.z); p[3] = (bf16_t)(u0.w * v0.w);
            p[4] = (bf16_t)(u1.x * v1.x); p[5] = (bf16_t)(u1.y * v1.y);
            p[6] = (bf16_t)(u1.z * v1.z); p[7] = (bf16_t)(u1.w * v1.w);
            *(bf16x8*)&X[srow * 264 + k0] = p;
        }
    }

    floatx4 acc[4][4];
    #pragma unroll
    for (int i = 0; i < 4; ++i)
        #pragma unroll
        for (int j = 0; j < 4; ++j)
            acc[i][j] = (floatx4){0.f, 0.f, 0.f, 0.f};

    __syncthreads();   // barrier 1: A staged

    // ---- GEMM1: A from LDS, B direct from global (L2-hot), no barriers ----
    #pragma unroll 2
    for (int kc = 0; kc < 8; ++kc) {
        const int k0 = kc * 32 + quad * 8;
        bf16x8 af[4], bfr[4];
        #pragma unroll
        for (int j = 0; j < 4; ++j)
            bfr[j] = *(const bf16x8*)(Wt1 + (size_t)(wc * 64 + j * 16 + l16) * 256 + k0);
        #pragma unroll
        for (int i = 0; i < 4; ++i)
            af[i] = *(const bf16x8*)(&X[(i * 16 + l16) * 264 + k0]);
        #pragma unroll
        for (int i = 0; i < 4; ++i)
            #pragma unroll
            for (int j = 0; j < 4; ++j)
                acc[i][j] = __builtin_amdgcn_mfma_f32_16x16x32_bf16(
                                af[i], bfr[j], acc[i][j], 0, 0, 0);
    }

    __syncthreads();   // barrier 2: all A reads done, X reusable for g

    // ---- epilogue 1: g tile -> X (bf16) ----
    #pragma unroll
    for (int j = 0; j < 4; ++j) {
        int col  = wc * 64 + j * 16 + l16;
        float bv = b1[col];
        #pragma unroll
        for (int i = 0; i < 4; ++i)
            #pragma unroll
            for (int r = 0; r < 4; ++r) {
                int row = i * 16 + quad * 4 + r;
                X[row * 264 + col] = (bf16_t)fmaxf(acc[i][j][r] + bv, 0.f);
            }
    }
    #pragma unroll
    for (int i = 0; i < 4; ++i)
        #pragma unroll
        for (int j = 0; j < 4; ++j)
            acc[i][j] = (floatx4){0.f, 0.f, 0.f, 0.f};
    if (tid < 64) rowacc[tid] = 0.f;

    __syncthreads();   // barrier 3: g visible + rowacc init

    // ---- GEMM2: g @ M; A from LDS, B direct from global, no barriers ----
    #pragma unroll 2
    for (int kc = 0; kc < 8; ++kc) {
        const int k0 = kc * 32 + quad * 8;
        bf16x8 af[4], bfr[4];
        #pragma unroll
        for (int j = 0; j < 4; ++j)
            bfr[j] = *(const bf16x8*)(Mt + (size_t)(wc * 64 + j * 16 + l16) * 256 + k0);
        #pragma unroll
        for (int i = 0; i < 4; ++i)
            af[i] = *(const bf16x8*)(&X[(i * 16 + l16) * 264 + k0]);
        #pragma unroll
        for (int i = 0; i < 4; ++i)
            #pragma unroll
            for (int j = 0; j < 4; ++j)
                acc[i][j] = __builtin_amdgcn_mfma_f32_16x16x32_bf16(
                                af[i], bfr[j], acc[i][j], 0, 0, 0);
    }

    // ---- final epilogue: +cvec +T2[xcn], relu, dot w2, row-reduce ----
    int xv[16];
    #pragma unroll
    for (int i = 0; i < 4; ++i)
        #pragma unroll
        for (int r = 0; r < 4; ++r)
            xv[i * 4 + r] = xcn[e0 + i * 16 + quad * 4 + r];

    float pr[16];
    #pragma unroll
    for (int t = 0; t < 16; ++t) pr[t] = 0.f;
    #pragma unroll
    for (int j = 0; j < 4; ++j) {
        int col  = wc * 64 + j * 16 + l16;
        float cv = cvec[col];
        float wv = w2[col];
        #pragma unroll
        for (int i = 0; i < 4; ++i)
            #pragma unroll
            for (int r = 0; r < 4; ++r) {
                float t2v = T2[(size_t)xv[i * 4 + r] * 256 + col];
                float v = fmaxf(acc[i][j][r] + cv + t2v, 0.f);
                pr[i * 4 + r] += v * wv;
            }
    }
    #pragma unroll
    for (int off = 1; off < 16; off <<= 1)
        #pragma unroll
        for (int t = 0; t < 16; ++t)
            pr[t] += __shfl_xor(pr[t], off, 64);
    if (l16 == 0) {
        #pragma unroll
        for (int i = 0; i < 4; ++i)
            #pragma unroll
            for (int r = 0; r < 4; ++r)
                atomicAdd(&rowacc[i * 16 + quad * 4 + r], pr[i * 4 + r]);
    }
    __syncthreads();
    if (tid < 64) out[e0 + tid] = rowacc[tid] + b2s[0];
}

extern "C" void kernel_launch(void* const* d_in, const int* in_sizes, int n_in,
                              void* d_out, int out_size, void* d_ws, size_t ws_size,
                              hipStream_t stream) {
    const float* x      = (const float*)d_in[0];
    const int*   nbr    = (const int*)  d_in[1];
    const int*   tar    = (const int*)  d_in[2];
    const float* beta   = (const float*)d_in[3];
    const float* cn_w1  = (const float*)d_in[4];
    const float* cn_b1  = (const float*)d_in[5];
    const float* cn_w2  = (const float*)d_in[6];
    const float* cn_b2  = (const float*)d_in[7];
    const float* cn_w3  = (const float*)d_in[8];
    const float* cn_b3  = (const float*)d_in[9];
    const float* ij_w1  = (const float*)d_in[10];
    const float* ij_b1  = (const float*)d_in[11];
    const float* ij_w2  = (const float*)d_in[12];
    const float* ij_b2  = (const float*)d_in[13];
    const float* lin_w1 = (const float*)d_in[14];
    const float* lin_b1 = (const float*)d_in[15];
    const float* lin_w2 = (const float*)d_in[16];
    const float* lin_b2 = (const float*)d_in[17];

    char* ws = (char*)d_ws;
    float*  T2    = (float*) (ws + 0);        // 512*256*4  = 524288
    int*    xcn   = (int*)   (ws + 524288);   // E*4        = 524288
    bf16_t* Wt1   = (bf16_t*)(ws + 1048576);  // 256*256*2  = 131072
    bf16_t* Mt    = (bf16_t*)(ws + 1179648);  // 256*256*2  = 131072
    float*  cvec  = (float*) (ws + 1310720);  // 256*4

    pre_kernel<<<1088 + EE / 4, 256, 0, stream>>>(
        nbr, tar, xcn, ij_w1, Wt1, ij_w2, lin_w1, Mt,
        ij_b2, lin_b1, cvec,
        cn_w1, cn_b1, cn_w2, cn_b2, cn_w3, cn_b3, beta, T2);
    fused_kernel<<<EE / 64, 256, 0, stream>>>(x, tar, Wt1, ij_b1, Mt, cvec,
                                              T2, xcn, lin_w2, lin_b2,
                                              (float*)d_out);
}

// Round 7
// 372.420 us; speedup vs baseline: 1.2785x; 1.0495x over previous
//
#include <hip/hip_runtime.h>
#include <hip/hip_bf16.h>
#include <stdint.h>

#define EE 131072
#define DDEG 64

typedef __bf16 bf16_t;
typedef bf16_t bf16x8 __attribute__((ext_vector_type(8)));
typedef float floatx4 __attribute__((ext_vector_type(4)));

// ---------------- CN pair-count: one wave per edge, scalar b-row ----------------
__global__ __launch_bounds__(256)
void cn_kernel(const int* __restrict__ nbr, const int* __restrict__ tar,
               int* __restrict__ xcn) {
    int wid  = (blockIdx.x * 256 + threadIdx.x) >> 6;
    int lane = threadIdx.x & 63;
    int s = __builtin_amdgcn_readfirstlane(tar[wid]);
    int d = __builtin_amdgcn_readfirstlane(tar[EE + wid]);
    int a = nbr[(size_t)s * DDEG + lane];                  // coalesced 256B row
    const int* __restrict__ brow = nbr + (size_t)d * DDEG; // uniform -> s_load
    int cnt = 0;
    #pragma unroll
    for (int k = 0; k < 64; ++k)
        cnt += __builtin_popcountll(__ballot(a == brow[k]));
    if (lane == 0) xcn[wid] = cnt;
}

// ---------------- prep: transpose | Mt | cvec | T2 v=0..511 | x->bf16 --------
// grid: [0,64) transpose, [64,320) Mt, [320,576) cvec, [576,1088) T2,
//       [1088,1088+6250) xb conversion.
__global__ __launch_bounds__(256)
void prep_kernel(const float* __restrict__ x, bf16_t* __restrict__ xb,
                 const float* __restrict__ ij_w1, bf16_t* __restrict__ Wt1,
                 const float* __restrict__ w2, const float* __restrict__ lw1,
                 bf16_t* __restrict__ Mt,
                 const float* __restrict__ b2, const float* __restrict__ lb1,
                 float* __restrict__ cvec,
                 const float* __restrict__ cw1, const float* __restrict__ cb1,
                 const float* __restrict__ cw2, const float* __restrict__ cb2,
                 const float* __restrict__ cw3, const float* __restrict__ cb3,
                 const float* __restrict__ beta, float* __restrict__ T2) {
    __shared__ __align__(16) char arena[33792];
    const int bid = blockIdx.x;
    const int t = threadIdx.x;

    if (bid >= 1088) {
        // ---- xb = bf16(x), 16 elements per thread ----
        size_t base = (size_t)(bid - 1088) * 4096 + (size_t)t * 16;
        float4 a0 = *(const float4*)(x + base);
        float4 a1 = *(const float4*)(x + base + 4);
        float4 a2 = *(const float4*)(x + base + 8);
        float4 a3 = *(const float4*)(x + base + 12);
        bf16x8 o0, o1;
        o0[0] = (bf16_t)a0.x; o0[1] = (bf16_t)a0.y; o0[2] = (bf16_t)a0.z; o0[3] = (bf16_t)a0.w;
        o0[4] = (bf16_t)a1.x; o0[5] = (bf16_t)a1.y; o0[6] = (bf16_t)a1.z; o0[7] = (bf16_t)a1.w;
        o1[0] = (bf16_t)a2.x; o1[1] = (bf16_t)a2.y; o1[2] = (bf16_t)a2.z; o1[3] = (bf16_t)a2.w;
        o1[4] = (bf16_t)a3.x; o1[5] = (bf16_t)a3.y; o1[6] = (bf16_t)a3.z; o1[7] = (bf16_t)a3.w;
        *(bf16x8*)(xb + base)     = o0;
        *(bf16x8*)(xb + base + 8) = o1;
        return;
    }

    if (bid < 64) {
        // ---- transpose ij_w1 fp32[k][n] -> bf16 Wt1[n][k] ----
        float (*tile)[33] = (float (*)[33])arena;
        int bx = bid & 7, by = bid >> 3;
        int tx = t & 31, ty = t >> 5;
        #pragma unroll
        for (int r = 0; r < 32; r += 8)
            tile[ty + r][tx] = ij_w1[(by * 32 + ty + r) * 256 + bx * 32 + tx];
        __syncthreads();
        #pragma unroll
        for (int r = 0; r < 32; r += 8)
            Wt1[(bx * 32 + ty + r) * 256 + by * 32 + tx] = (bf16_t)tile[tx][ty + r];
    } else if (bid < 320) {
        // ---- Mt[b][a] = sum_c ij_w2[a][c] * lin_w1[c][b] (bf16 [n][k]) ----
        float (*S)[33] = (float (*)[33])arena;
        int b = bid - 64;
        int cc = t & 31, abase = t >> 5;
        float acc = 0.f;
        for (int c0 = 0; c0 < 256; c0 += 32) {
            __syncthreads();
            #pragma unroll
            for (int r = 0; r < 32; ++r) {
                int a = r * 8 + abase;
                S[a][cc] = w2[a * 256 + c0 + cc];
            }
            __syncthreads();
            #pragma unroll 8
            for (int c2 = 0; c2 < 32; ++c2) {
                float wv = lw1[(c0 + c2) * 256 + b];   // uniform -> scalar
                acc += S[t][c2] * wv;
            }
        }
        Mt[(size_t)b * 256 + t] = (bf16_t)acc;
    } else if (bid < 576) {
        // ---- cvec[b] = ij_b2 @ lin_w1 + lin_b1 ----
        float* red = (float*)arena;
        int b = bid - 320;
        red[t] = b2[t] * lw1[t * 256 + b];
        __syncthreads();
        for (int s = 128; s > 0; s >>= 1) {
            if (t < s) red[t] += red[t + s];
            __syncthreads();
        }
        if (t == 0) cvec[b] = red[0] + lb1[b];
    } else {
        // ---- T2[v] = (cn_mlp(v) * beta) @ lin_w1, v = 0..511 ----
        float* t1 = (float*)arena;
        float* t2 = (float*)(arena + 1024);
        float* t3 = (float*)(arena + 2048);
        int v = bid - 576;
        float fv = (float)v;
        t1[t] = fmaxf(fv * cw1[t] + cb1[t], 0.f);
        __syncthreads();
        float s = cb2[t];
        for (int k = 0; k < 256; ++k) s += t1[k] * cw2[k * 256 + t];
        t2[t] = fmaxf(s, 0.f);
        __syncthreads();
        s = cb3[t];
        for (int k = 0; k < 256; ++k) s += t2[k] * cw3[k * 256 + t];
        t3[t] = s * beta[0];
        __syncthreads();
        s = 0.f;
        for (int k = 0; k < 256; ++k) s += t3[k] * lw1[k * 256 + t];
        T2[(size_t)v * 256 + t] = s;
    }
}

// ---------------- fused: A staged ONCE (bf16 gather, deep MLP), 3 barriers ----
// g = relu((xi*xj)@W1 + b1); z = relu(g@M + cvec + T2[xcn]); out = z@w2 + b2s
__global__ __launch_bounds__(256, 4)
void fused_kernel(const bf16_t* __restrict__ xb, const int* __restrict__ tar,
                  const bf16_t* __restrict__ Wt1, const float* __restrict__ b1,
                  const bf16_t* __restrict__ Mt, const float* __restrict__ cvec,
                  const float* __restrict__ T2, const int* __restrict__ xcn,
                  const float* __restrict__ w2, const float* __restrict__ b2s,
                  float* __restrict__ out) {
    __shared__ __align__(16) bf16_t X[64 * 264];   // A tile, then g tile
    __shared__ float rowacc[64];

    const int tid  = threadIdx.x;
    const int lane = tid & 63;
    const int wc   = tid >> 6;          // wave = col quarter 0..3
    const int quad = lane >> 4;
    const int l16  = lane & 15;
    const int e0   = blockIdx.x * 64;

    // ---- stage A = bf16(xi * xj), full K=256: issue ALL loads, then convert --
    {
        const int srow   = tid >> 2;       // 4 threads per row
        const int skbase = (tid & 3) * 8;
        int e = e0 + srow;
        const bf16_t* xi = xb + (size_t)tar[e] * 256 + skbase;
        const bf16_t* xj = xb + (size_t)tar[EE + e] * 256 + skbase;
        bf16x8 ui[8], vj[8];
        #pragma unroll
        for (int kc = 0; kc < 8; ++kc) {
            ui[kc] = *(const bf16x8*)(xi + kc * 32);
            vj[kc] = *(const bf16x8*)(xj + kc * 32);
        }
        #pragma unroll
        for (int kc = 0; kc < 8; ++kc) {
            bf16x8 p;
            #pragma unroll
            for (int m = 0; m < 8; ++m)
                p[m] = (bf16_t)((float)ui[kc][m] * (float)vj[kc][m]);
            *(bf16x8*)&X[srow * 264 + kc * 32 + skbase] = p;
        }
    }

    floatx4 acc[4][4];
    #pragma unroll
    for (int i = 0; i < 4; ++i)
        #pragma unroll
        for (int j = 0; j < 4; ++j)
            acc[i][j] = (floatx4){0.f, 0.f, 0.f, 0.f};

    __syncthreads();   // barrier 1: A staged

    // ---- GEMM1: A from LDS, B direct from global (L2-hot) ----
    #pragma unroll 2
    for (int kc = 0; kc < 8; ++kc) {
        const int k0 = kc * 32 + quad * 8;
        bf16x8 af[4], bfr[4];
        #pragma unroll
        for (int j = 0; j < 4; ++j)
            bfr[j] = *(const bf16x8*)(Wt1 + (size_t)(wc * 64 + j * 16 + l16) * 256 + k0);
        #pragma unroll
        for (int i = 0; i < 4; ++i)
            af[i] = *(const bf16x8*)(&X[(i * 16 + l16) * 264 + k0]);
        #pragma unroll
        for (int i = 0; i < 4; ++i)
            #pragma unroll
            for (int j = 0; j < 4; ++j)
                acc[i][j] = __builtin_amdgcn_mfma_f32_16x16x32_bf16(
                                af[i], bfr[j], acc[i][j], 0, 0, 0);
    }

    __syncthreads();   // barrier 2: all A reads done, X reusable for g

    // ---- epilogue 1: g tile -> X (bf16) ----
    #pragma unroll
    for (int j = 0; j < 4; ++j) {
        int col  = wc * 64 + j * 16 + l16;
        float bv = b1[col];
        #pragma unroll
        for (int i = 0; i < 4; ++i)
            #pragma unroll
            for (int r = 0; r < 4; ++r) {
                int row = i * 16 + quad * 4 + r;
                X[row * 264 + col] = (bf16_t)fmaxf(acc[i][j][r] + bv, 0.f);
            }
    }
    #pragma unroll
    for (int i = 0; i < 4; ++i)
        #pragma unroll
        for (int j = 0; j < 4; ++j)
            acc[i][j] = (floatx4){0.f, 0.f, 0.f, 0.f};
    if (tid < 64) rowacc[tid] = 0.f;

    __syncthreads();   // barrier 3: g visible + rowacc init

    // ---- GEMM2: g @ M; A from LDS, B direct from global ----
    #pragma unroll 2
    for (int kc = 0; kc < 8; ++kc) {
        const int k0 = kc * 32 + quad * 8;
        bf16x8 af[4], bfr[4];
        #pragma unroll
        for (int j = 0; j < 4; ++j)
            bfr[j] = *(const bf16x8*)(Mt + (size_t)(wc * 64 + j * 16 + l16) * 256 + k0);
        #pragma unroll
        for (int i = 0; i < 4; ++i)
            af[i] = *(const bf16x8*)(&X[(i * 16 + l16) * 264 + k0]);
        #pragma unroll
        for (int i = 0; i < 4; ++i)
            #pragma unroll
            for (int j = 0; j < 4; ++j)
                acc[i][j] = __builtin_amdgcn_mfma_f32_16x16x32_bf16(
                                af[i], bfr[j], acc[i][j], 0, 0, 0);
    }

    // ---- final epilogue: +cvec +T2[xcn], relu, dot w2, row-reduce ----
    int xv[16];
    #pragma unroll
    for (int i = 0; i < 4; ++i)
        #pragma unroll
        for (int r = 0; r < 4; ++r) {
            int v = xcn[e0 + i * 16 + quad * 4 + r];
            xv[i * 4 + r] = v < 511 ? v : 511;   // memory-safety clamp
        }

    float pr[16];
    #pragma unroll
    for (int t = 0; t < 16; ++t) pr[t] = 0.f;
    #pragma unroll
    for (int j = 0; j < 4; ++j) {
        int col  = wc * 64 + j * 16 + l16;
        float cv = cvec[col];
        float wv = w2[col];
        #pragma unroll
        for (int i = 0; i < 4; ++i)
            #pragma unroll
            for (int r = 0; r < 4; ++r) {
                float t2v = T2[(size_t)xv[i * 4 + r] * 256 + col];
                float v = fmaxf(acc[i][j][r] + cv + t2v, 0.f);
                pr[i * 4 + r] += v * wv;
            }
    }
    #pragma unroll
    for (int off = 1; off < 16; off <<= 1)
        #pragma unroll
        for (int t = 0; t < 16; ++t)
            pr[t] += __shfl_xor(pr[t], off, 64);
    if (l16 == 0) {
        #pragma unroll
        for (int i = 0; i < 4; ++i)
            #pragma unroll
            for (int r = 0; r < 4; ++r)
                atomicAdd(&rowacc[i * 16 + quad * 4 + r], pr[i * 4 + r]);
    }
    __syncthreads();
    if (tid < 64) out[e0 + tid] = rowacc[tid] + b2s[0];
}

extern "C" void kernel_launch(void* const* d_in, const int* in_sizes, int n_in,
                              void* d_out, int out_size, void* d_ws, size_t ws_size,
                              hipStream_t stream) {
    const float* x      = (const float*)d_in[0];
    const int*   nbr    = (const int*)  d_in[1];
    const int*   tar    = (const int*)  d_in[2];
    const float* beta   = (const float*)d_in[3];
    const float* cn_w1  = (const float*)d_in[4];
    const float* cn_b1  = (const float*)d_in[5];
    const float* cn_w2  = (const float*)d_in[6];
    const float* cn_b2  = (const float*)d_in[7];
    const float* cn_w3  = (const float*)d_in[8];
    const float* cn_b3  = (const float*)d_in[9];
    const float* ij_w1  = (const float*)d_in[10];
    const float* ij_b1  = (const float*)d_in[11];
    const float* ij_w2  = (const float*)d_in[12];
    const float* ij_b2  = (const float*)d_in[13];
    const float* lin_w1 = (const float*)d_in[14];
    const float* lin_b1 = (const float*)d_in[15];
    const float* lin_w2 = (const float*)d_in[16];
    const float* lin_b2 = (const float*)d_in[17];

    char* ws = (char*)d_ws;
    float*  T2    = (float*) (ws + 0);        // 512*256*4  = 524288
    int*    xcn   = (int*)   (ws + 524288);   // E*4        = 524288
    bf16_t* Wt1   = (bf16_t*)(ws + 1048576);  // 256*256*2  = 131072
    bf16_t* Mt    = (bf16_t*)(ws + 1179648);  // 256*256*2  = 131072
    float*  cvec  = (float*) (ws + 1310720);  // 256*4 -> pad to 1312768
    bf16_t* xb    = (bf16_t*)(ws + 1312768);  // 100000*256*2 = 51.2 MB

    cn_kernel<<<EE / 4, 256, 0, stream>>>(nbr, tar, xcn);
    prep_kernel<<<1088 + 6250, 256, 0, stream>>>(
        x, xb, ij_w1, Wt1, ij_w2, lin_w1, Mt,
        ij_b2, lin_b1, cvec,
        cn_w1, cn_b1, cn_w2, cn_b2, cn_w3, cn_b3, beta, T2);
    fused_kernel<<<EE / 64, 256, 0, stream>>>(xb, tar, Wt1, ij_b1, Mt, cvec,
                                              T2, xcn, lin_w2, lin_b2,
                                              (float*)d_out);
}